// Round 6
// baseline (116.471 us; speedup 1.0000x reference)
//
#include <hip/hip_runtime.h>

// Problem constants (from reference setup_inputs) — all tensors are fp32.
#define BATCH 16
#define NVEC 1024
#define NDIM 64
#define NHID 32
#define NW   10
#define NCLS 10
#define NOFF 11      // diag + 10 power-of-2 offsets (chord mask: 11 nnz/row)
#define WPAD 12      // padded weights-per-row so k_chain reads 3x float4
#define NCHUNK (NDIM / 4)   // 16 d-chunks in k_chain
#define W2PAD 36     // padded row length for the staged-W2 LDS cache
#define NROW 8       // n-rows per k_weights block (4 per thread, 2 waves)
#define NSLOT 64     // staged W2T rows: [0,24) u ({32,64,128,256,512}+[0,8))

// ---------------------------------------------------------------------------
// Kernel 1: all sparse chord weights, all 10 layers.
// Block = (layer i, 8 rows, ALL 16 b); grid (128, 10) = 1280 blocks of 128
// threads = 5 blocks/CU. Thread = (jq = t&3, b = (t>>2)&15, nl = t>>6)
// computing 4 consecutive rows x 8 hidden units -> h[4][8].
//
// Session journal:
//  * ROUND-6 HYPOTHESIS: rounds 4/5 ran at 2 waves/SIMD because the 4-row
//    unroll-2 loop exceeded 128 VGPR (launch_bounds(128,2) allows 256).
//    Fix: launch_bounds(128, 4) hard-caps VGPR at 128 (>=4 waves/SIMD,
//    8 blocks/CU residable) + drop unroll-2 to shrink the live set so the
//    cap is met without scratch spills.
//  * jq in lane bits 0-1: quarter-dot reduction = shfl_xor(1)/(2) DPP
//    quad_perm (pure VALU). Reduction order (q0+q1)+(q2+q3) preserved.
//  * round-2 post-mortem: NEVER fuse the final reduction via __threadfence
//    — it is a whole-L2 writeback/inv on gfx950 (cost +50 µs).
// ---------------------------------------------------------------------------
__global__ __launch_bounds__(128, 4) void k_weights(
    const float* __restrict__ data,   // [B][NVEC][NDIM]
    const float* __restrict__ fW1,    // [NW][NDIM][NHID]
    const float* __restrict__ fb1,    // [NW][NHID]
    const float* __restrict__ fW2,    // [NW][NHID][NVEC]
    const float* __restrict__ fb2,    // [NW][NVEC]
    float* __restrict__ Wsp)          // [NW][B][NVEC][WPAD]
{
    const int i = blockIdx.y;
    const int nbase = blockIdx.x * NROW;
    const int t = threadIdx.x;        // 0..127
    const int jq = t & 3;
    const int b  = (t >> 2) & 15;
    const int nl = t >> 6;            // wave index 0..1 (4 rows each)
    const int j0 = jq * 8;

    __shared__ __align__(16) float sW1[NDIM * NHID];        // [d][j], 8 KB
    __shared__ float sb1[NHID];
    __shared__ __align__(16) float sW2r[NSLOT * W2PAD];     // 9.2 KB
    __shared__ float sb2[NSLOT];                            // fb2 at slots
    __shared__ __align__(16) float rws[NROW * BATCH * WPAD];// 6 KB

    {
        const float4* w1v = (const float4*)(fW1 + (size_t)i * NDIM * NHID);
        float4* s4 = (float4*)sW1;
        for (int k = t; k < NDIM * NHID / 4; k += 128) s4[k] = w1v[k];
        if (t < NHID) sb1[t] = fb1[i * NHID + t];

        // stage the 64 needed fW2 columns (rows of W2^T) into LDS.
        // lane = slot (s fast) so each wave's 64 loads hit contiguous m
        // segments (24 contiguous + 5 groups of 8).
        const int s  = t & 63;
        const int j2 = t >> 6;        // 0..1
        int k = (s < 24) ? s : ((32 << ((s - 24) >> 3)) + ((s - 24) & 7));
        int m = (nbase + k) & (NVEC - 1);
        const float* w2 = fW2 + (size_t)i * NHID * NVEC + m;
        #pragma unroll
        for (int jj = 0; jj < 16; ++jj)
            sW2r[s * W2PAD + (j2 + jj * 2)] = w2[(size_t)(j2 + jj * 2) * NVEC];
        if (t < NSLOT) sb2[s] = fb2[(size_t)i * NVEC + m];

        // zero the WPAD pad slot so Wsp never carries stale-LDS bits
        rws[t * WPAD + (WPAD - 1)] = 0.0f;
    }
    __syncthreads();

    float h[4][8];
    #pragma unroll
    for (int r = 0; r < 4; ++r)
        #pragma unroll
        for (int jj = 0; jj < 8; ++jj) h[r][jj] = sb1[j0 + jj];

    const int n0 = nbase + nl * 4;    // 4 consecutive rows -> one base ptr
    const float4* rowp = (const float4*)(data + ((size_t)(b * NVEC) + n0) * NDIM);

    for (int g = 0; g < 16; ++g) {    // 4 d-dims per iteration
        float4 a0 = rowp[g];
        float4 a1 = rowp[16 + g];
        float4 a2 = rowp[32 + g];
        float4 a3 = rowp[48 + g];
        const float as[4][4] = {{a0.x, a0.y, a0.z, a0.w},
                                {a1.x, a1.y, a1.z, a1.w},
                                {a2.x, a2.y, a2.z, a2.w},
                                {a3.x, a3.y, a3.z, a3.w}};
        #pragma unroll
        for (int dk = 0; dk < 4; ++dk) {
            const float4* wp = (const float4*)(&sW1[(g * 4 + dk) * NHID + j0]);
            float4 w0 = wp[0], w1 = wp[1];
            const float wf[8] = {w0.x, w0.y, w0.z, w0.w, w1.x, w1.y, w1.z, w1.w};
            #pragma unroll
            for (int jj = 0; jj < 8; ++jj) {
                h[0][jj] += as[0][dk] * wf[jj];
                h[1][jj] += as[1][dk] * wf[jj];
                h[2][jj] += as[2][dk] * wf[jj];
                h[3][jj] += as[3][dk] * wf[jj];
            }
        }
    }

    // exact gelu (bit-match with reference)
    #pragma unroll
    for (int r = 0; r < 4; ++r)
        #pragma unroll
        for (int jj = 0; jj < 8; ++jj) {
            float x = h[r][jj];
            h[r][jj] = 0.5f * x * (1.0f + erff(x * 0.70710678118654752f));
        }

    // sparse gather: W[n, (n+off)&1023] = h[n] . W2T[(n+off)&1023] + b2
    const int rbase = nl * 4;         // 0 or 4
    #pragma unroll
    for (int r = 0; r < 4; ++r) {
        #pragma unroll
        for (int o = 0; o < NOFF; ++o) {
            int slot;
            if (o == 0) slot = rbase + r;
            else {
                int off = 1 << (o - 1);
                slot = (off <= 16) ? (rbase + r + off)
                                   : (24 + 8 * (o - 6) + rbase + r);
            }
            const float4* gp = (const float4*)(sW2r + slot * W2PAD + j0);
            float4 g0 = gp[0], g1 = gp[1];
            float w = h[r][0] * g0.x + h[r][1] * g0.y + h[r][2] * g0.z + h[r][3] * g0.w
                    + h[r][4] * g1.x + h[r][5] * g1.y + h[r][6] * g1.z + h[r][7] * g1.w;
            w += __shfl_xor(w, 1, 64);    // combine jq bit 0 (DPP quad_perm)
            w += __shfl_xor(w, 2, 64);    // combine jq bit 1 (DPP quad_perm)
            if (jq == (o & 3))
                rws[(b * NROW + rbase + r) * WPAD + o] = w + sb2[slot];
        }
    }
    __syncthreads();

    // coalesced write-out: 128 rows x 12 floats = 384 float4
    {
        const float4* rv = (const float4*)rws;
        #pragma unroll
        for (int k = t; k < NROW * BATCH * 3; k += 128) {
            int row = k / 3, comp = k - row * 3;
            int bb = row >> 3, rr = row & 7;
            float4* dst = (float4*)(Wsp +
                ((size_t)(i * BATCH + bb) * NVEC + nbase + rr) * WPAD + comp * 4);
            *dst = rv[k];
        }
    }
}

// ---------------------------------------------------------------------------
// Kernel 2: FUSED 10-layer chain + final-projection partials.
// Block = (b, 4-dim chunk): V[1024][4] slice in LDS. 512 threads; thread n
// owns rows n AND n+512 in registers -> the offset-512 gather is a REGISTER
// read for both rows. Cross-wave reduction mapped so sred[w] (w=0..15)
// holds bitwise the same 16 partials as the 16-wave version.
// XCD-aware mapping: all 16 chunk-blocks of a b land on one XCD (L2 reuse
// of the per-layer 48 KB Wsp slab).
// grid (256), block 512.  [unchanged from round 5 — known-good]
// ---------------------------------------------------------------------------
__global__ __launch_bounds__(512) void k_chain(
    const float* __restrict__ data,   // [B][NVEC][NDIM]
    const float* __restrict__ Wsp,    // [NW][B][NVEC][WPAD]
    const float* __restrict__ Wf,     // [NVEC*NDIM][NCLS]
    float* __restrict__ part)         // [B][NCHUNK][NCLS]
{
    const int lin   = blockIdx.x;
    const int xcd   = lin & 7;
    const int slot  = lin >> 3;             // 0..31
    const int b     = (xcd << 1) | (slot >> 4);
    const int chunk = slot & 15;
    const int d0    = chunk * 4;
    const int n     = threadIdx.x;          // 0..511
    const int n2    = n + 512;

    __shared__ float4 bufA[NVEC];
    __shared__ float4 bufB[NVEC];

    float4 v0own = *(const float4*)(data + ((size_t)(b * NVEC) + n)  * NDIM + d0);
    float4 v1own = *(const float4*)(data + ((size_t)(b * NVEC) + n2) * NDIM + d0);
    bufA[n]  = v0own;
    bufA[n2] = v1own;

    // prefetch layer NW-1 weights for both rows
    const float* wbase = Wsp + (size_t)((NW - 1) * BATCH + b) * NVEC * WPAD;
    const float4* wp0 = (const float4*)(wbase + (size_t)n  * WPAD);
    const float4* wp1 = (const float4*)(wbase + (size_t)n2 * WPAD);
    float4 wa0 = wp0[0], wb0 = wp0[1], wc0 = wp0[2];
    float4 wa1 = wp1[0], wb1 = wp1[1], wc1 = wp1[2];
    __syncthreads();

    float4* cur = bufA;
    float4* nxt = bufB;

    for (int l = 0; l < NW; ++l) {
        float4 na0, nb0, nc0, na1, nb1, nc1;
        if (l < NW - 1) {   // prefetch next layer (in flight across barrier)
            const float* nbase_p = Wsp + (size_t)((NW - 2 - l) * BATCH + b) * NVEC * WPAD;
            const float4* q0 = (const float4*)(nbase_p + (size_t)n  * WPAD);
            const float4* q1 = (const float4*)(nbase_p + (size_t)n2 * WPAD);
            na0 = q0[0]; nb0 = q0[1]; nc0 = q0[2];
            na1 = q1[0]; nb1 = q1[1]; nc1 = q1[2];
        }
        const float wg0[12] = {wa0.x, wa0.y, wa0.z, wa0.w,
                               wb0.x, wb0.y, wb0.z, wb0.w,
                               wc0.x, wc0.y, wc0.z, wc0.w};
        const float wg1[12] = {wa1.x, wa1.y, wa1.z, wa1.w,
                               wb1.x, wb1.y, wb1.z, wb1.w,
                               wc1.x, wc1.y, wc1.z, wc1.w};
        // row n (diag + offsets; offset 512 comes from v1own register)
        float4 acc0;
        acc0.x = v0own.x + wg0[0] * v0own.x;
        acc0.y = v0own.y + wg0[0] * v0own.y;
        acc0.z = v0own.z + wg0[0] * v0own.z;
        acc0.w = v0own.w + wg0[0] * v0own.w;
        #pragma unroll
        for (int o = 1; o < NOFF; ++o) {
            int off = 1 << (o - 1);
            float4 vv = (off == 512) ? v1own : cur[(n + off) & (NVEC - 1)];
            acc0.x += wg0[o] * vv.x; acc0.y += wg0[o] * vv.y;
            acc0.z += wg0[o] * vv.z; acc0.w += wg0[o] * vv.w;
        }
        // row n+512 (offset 512 wraps to row n -> v0own register)
        float4 acc1;
        acc1.x = v1own.x + wg1[0] * v1own.x;
        acc1.y = v1own.y + wg1[0] * v1own.y;
        acc1.z = v1own.z + wg1[0] * v1own.z;
        acc1.w = v1own.w + wg1[0] * v1own.w;
        #pragma unroll
        for (int o = 1; o < NOFF; ++o) {
            int off = 1 << (o - 1);
            float4 vv = (off == 512) ? v0own : cur[(n2 + off) & (NVEC - 1)];
            acc1.x += wg1[o] * vv.x; acc1.y += wg1[o] * vv.y;
            acc1.z += wg1[o] * vv.z; acc1.w += wg1[o] * vv.w;
        }
        nxt[n]  = acc0;
        nxt[n2] = acc1;
        v0own = acc0;
        v1own = acc1;
        __syncthreads();
        float4* tmp = cur; cur = nxt; nxt = tmp;
        if (l < NW - 1) {
            wa0 = na0; wb0 = nb0; wc0 = nc0;
            wa1 = na1; wb1 = nb1; wc1 = nc1;
        }
    }

    // fused final projection partials for both rows — from registers
    float p0[NCLS], p1[NCLS];
    #pragma unroll
    for (int c = 0; c < NCLS; ++c) { p0[c] = 0.0f; p1[c] = 0.0f; }
    {
        float vs0[4] = {v0own.x, v0own.y, v0own.z, v0own.w};
        float vs1[4] = {v1own.x, v1own.y, v1own.z, v1own.w};
        const float4* wfv0 = (const float4*)(Wf + ((size_t)(n  * NDIM + d0)) * NCLS);
        const float4* wfv1 = (const float4*)(Wf + ((size_t)(n2 * NDIM + d0)) * NCLS);
        float wf0[40], wf1[40];
        #pragma unroll
        for (int k = 0; k < 10; ++k) {
            float4 u0 = wfv0[k], u1 = wfv1[k];
            wf0[k * 4 + 0] = u0.x; wf0[k * 4 + 1] = u0.y;
            wf0[k * 4 + 2] = u0.z; wf0[k * 4 + 3] = u0.w;
            wf1[k * 4 + 0] = u1.x; wf1[k * 4 + 1] = u1.y;
            wf1[k * 4 + 2] = u1.z; wf1[k * 4 + 3] = u1.w;
        }
        #pragma unroll
        for (int d = 0; d < 4; ++d)
            #pragma unroll
            for (int cls = 0; cls < NCLS; ++cls) {
                p0[cls] += vs0[d] * wf0[d * NCLS + cls];
                p1[cls] += vs1[d] * wf1[d * NCLS + cls];
            }
    }

    // reduce -> 10 values; wave wv emits partials of old waves wv and wv+8
    const int lane = n & 63, wv = n >> 6;   // 8 waves
    float* sred = (float*)nxt;              // dead buffer
    #pragma unroll
    for (int cls = 0; cls < NCLS; ++cls) {
        float v0 = p0[cls];
        float v1 = p1[cls];
        #pragma unroll
        for (int s = 32; s > 0; s >>= 1) {
            v0 += __shfl_down(v0, s, 64);
            v1 += __shfl_down(v1, s, 64);
        }
        if (lane == 0) {
            sred[wv * NCLS + cls]       = v0;
            sred[(wv + 8) * NCLS + cls] = v1;
        }
    }
    __syncthreads();
    if (n < NCLS) {
        float s = 0.0f;
        #pragma unroll
        for (int w = 0; w < 16; ++w) s += sred[w * NCLS + n];
        part[(size_t)(b * NCHUNK + chunk) * NCLS + n] = s;
    }
}

// ---------------------------------------------------------------------------
__global__ __launch_bounds__(256) void k_finish(
    const float* __restrict__ part, const float* __restrict__ bias,
    float* __restrict__ out)
{
    int t = threadIdx.x;
    if (t < BATCH * NCLS) {
        int b = t / NCLS, cls = t % NCLS;
        float s = bias[cls];
        #pragma unroll
        for (int ch = 0; ch < NCHUNK; ++ch)
            s += part[(size_t)(b * NCHUNK + ch) * NCLS + cls];
        out[t] = s;
    }
}

// ---------------------------------------------------------------------------
extern "C" void kernel_launch(void* const* d_in, const int* in_sizes, int n_in,
                              void* d_out, int out_size, void* d_ws, size_t ws_size,
                              hipStream_t stream) {
    const float* data = (const float*)d_in[0];
    const float* fW1  = (const float*)d_in[1];
    const float* fb1  = (const float*)d_in[2];
    const float* fW2  = (const float*)d_in[3];
    const float* fb2  = (const float*)d_in[4];
    const float* fWf  = (const float*)d_in[5];
    const float* fbf  = (const float*)d_in[6];
    float* out = (float*)d_out;

    float* ws   = (float*)d_ws;
    float* Wsp  = ws;                                         // NW*B*NVEC*WPAD = 1,966,080 f
    float* part = Wsp + (size_t)NW * BATCH * NVEC * WPAD;     // B*NCHUNK*NCLS = 2,560 f

    k_weights<<<dim3(NVEC / NROW, NW), 128, 0, stream>>>(
        data, fW1, fb1, fW2, fb2, Wsp);
    k_chain<<<dim3(NCHUNK * BATCH), 512, 0, stream>>>(data, Wsp, fWf, part);
    k_finish<<<dim3(1), 256, 0, stream>>>(part, fbf, out);
}

// Round 7
// 116.402 us; speedup vs baseline: 1.0006x; 1.0006x over previous
//
#include <hip/hip_runtime.h>

// Problem constants (from reference setup_inputs) — all tensors are fp32.
#define BATCH 16
#define NVEC 1024
#define NDIM 64
#define NHID 32
#define NW   10
#define NCLS 10
#define NOFF 11      // diag + 10 power-of-2 offsets (chord mask: 11 nnz/row)
#define WPAD 12      // padded weights-per-row so k_chain reads 3x float4
#define NCHUNK (NDIM / 4)   // 16 d-chunks in k_chain
#define W2PAD 36     // padded row length for the staged-W2 LDS cache
#define NROW 8       // n-rows per k_weights block (4 per thread, 2 waves)
#define NSLOT 64     // staged W2T rows: [0,24) u ({32,64,128,256,512}+[0,8))

// ---------------------------------------------------------------------------
// Kernel 1: all sparse chord weights, all 10 layers.
// Block = (layer i, 8 rows, ALL 16 b); grid (128, 10), 128 threads.
// Thread = (jq = t&3, b = (t>>2)&15, nl = t>>6), 4 rows x 8 hidden -> h[4][8].
//
// Session journal:
//  * ROUND-7 THEORY: rounds 4-6 varied rows/thread, block size, grid
//    balance, VGPR caps — ALL neutral at ~40 µs (4x the ~10 µs pipe
//    model). The invariant was the fully-unrolled ~40 KB body (2048
//    FMAs + 32 erff + 44 gather stanzas) vs 32 KB I$: the kernel is
//    instruction-fetch bound. Fix: #pragma unroll 1 on the g-loop
//    (with 1-deep register prefetch of data so rolling exposes no L2
//    latency) and on the gather o-loop -> ~8 KB hot code. FP order
//    unchanged (bit-identical output).
//  * jq in lane bits 0-1: quarter-dot reduction = shfl_xor(1)/(2) DPP
//    quad_perm (pure VALU). Reduction order (q0+q1)+(q2+q3) preserved.
//  * round-2 post-mortem: NEVER fuse the final reduction via __threadfence
//    — it is a whole-L2 writeback/inv on gfx950 (cost +50 µs).
// ---------------------------------------------------------------------------
__global__ __launch_bounds__(128, 2) void k_weights(
    const float* __restrict__ data,   // [B][NVEC][NDIM]
    const float* __restrict__ fW1,    // [NW][NDIM][NHID]
    const float* __restrict__ fb1,    // [NW][NHID]
    const float* __restrict__ fW2,    // [NW][NHID][NVEC]
    const float* __restrict__ fb2,    // [NW][NVEC]
    float* __restrict__ Wsp)          // [NW][B][NVEC][WPAD]
{
    const int i = blockIdx.y;
    const int nbase = blockIdx.x * NROW;
    const int t = threadIdx.x;        // 0..127
    const int jq = t & 3;
    const int b  = (t >> 2) & 15;
    const int nl = t >> 6;            // wave index 0..1 (4 rows each)
    const int j0 = jq * 8;

    __shared__ __align__(16) float sW1[NDIM * NHID];        // [d][j], 8 KB
    __shared__ float sb1[NHID];
    __shared__ __align__(16) float sW2r[NSLOT * W2PAD];     // 9.2 KB
    __shared__ float sb2[NSLOT];                            // fb2 at slots
    __shared__ __align__(16) float rws[NROW * BATCH * WPAD];// 6 KB

    {
        const float4* w1v = (const float4*)(fW1 + (size_t)i * NDIM * NHID);
        float4* s4 = (float4*)sW1;
        for (int k = t; k < NDIM * NHID / 4; k += 128) s4[k] = w1v[k];
        if (t < NHID) sb1[t] = fb1[i * NHID + t];

        // stage the 64 needed fW2 columns (rows of W2^T) into LDS.
        const int s  = t & 63;
        const int j2 = t >> 6;        // 0..1
        int k = (s < 24) ? s : ((32 << ((s - 24) >> 3)) + ((s - 24) & 7));
        int m = (nbase + k) & (NVEC - 1);
        const float* w2 = fW2 + (size_t)i * NHID * NVEC + m;
        #pragma unroll 1
        for (int jj = 0; jj < 16; ++jj)
            sW2r[s * W2PAD + (j2 + jj * 2)] = w2[(size_t)(j2 + jj * 2) * NVEC];
        if (t < NSLOT) sb2[s] = fb2[(size_t)i * NVEC + m];

        // zero the WPAD pad slot so Wsp never carries stale-LDS bits
        rws[t * WPAD + (WPAD - 1)] = 0.0f;
    }
    __syncthreads();

    float h[4][8];
    #pragma unroll
    for (int r = 0; r < 4; ++r)
        #pragma unroll
        for (int jj = 0; jj < 8; ++jj) h[r][jj] = sb1[j0 + jj];

    const int n0 = nbase + nl * 4;    // 4 consecutive rows -> one base ptr
    const float4* rowp = (const float4*)(data + ((size_t)(b * NVEC) + n0) * NDIM);

    // rolled g-loop with 1-deep data prefetch: ~160-inst body, I$-friendly
    float4 c0 = rowp[0], c1 = rowp[16], c2 = rowp[32], c3 = rowp[48];
    #pragma unroll 1
    for (int g = 0; g < 16; ++g) {
        const int gn = (g + 1) & 15;              // wrap: always in-bounds
        float4 p0 = rowp[gn];
        float4 p1 = rowp[16 + gn];
        float4 p2 = rowp[32 + gn];
        float4 p3 = rowp[48 + gn];
        const float as0[4] = {c0.x, c0.y, c0.z, c0.w};
        const float as1[4] = {c1.x, c1.y, c1.z, c1.w};
        const float as2[4] = {c2.x, c2.y, c2.z, c2.w};
        const float as3[4] = {c3.x, c3.y, c3.z, c3.w};
        #pragma unroll
        for (int dk = 0; dk < 4; ++dk) {
            const float4* wp = (const float4*)(&sW1[(g * 4 + dk) * NHID + j0]);
            float4 w0 = wp[0], w1 = wp[1];
            const float wf[8] = {w0.x, w0.y, w0.z, w0.w, w1.x, w1.y, w1.z, w1.w};
            #pragma unroll
            for (int jj = 0; jj < 8; ++jj) {
                h[0][jj] += as0[dk] * wf[jj];
                h[1][jj] += as1[dk] * wf[jj];
                h[2][jj] += as2[dk] * wf[jj];
                h[3][jj] += as3[dk] * wf[jj];
            }
        }
        c0 = p0; c1 = p1; c2 = p2; c3 = p3;
    }

    // exact gelu (bit-match with reference) — kept inline/unrolled: passing
    // h by address to a helper would force h to scratch (rule: no
    // runtime-indexed/addressed register arrays).
    #pragma unroll
    for (int r = 0; r < 4; ++r)
        #pragma unroll
        for (int jj = 0; jj < 8; ++jj) {
            float x = h[r][jj];
            h[r][jj] = 0.5f * x * (1.0f + erff(x * 0.70710678118654752f));
        }

    // sparse gather: W[n, (n+off)&1023] = h[n] . W2T[(n+off)&1023] + b2
    // o-loop rolled (slot arithmetic at runtime); r-loop unrolled so all
    // h[r][jj] indices stay compile-time constants.
    const int rbase = nl * 4;         // 0 or 4
    #pragma unroll 1
    for (int o = 0; o < NOFF; ++o) {
        const int off   = (o == 0) ? 0 : (1 << (o - 1));
        const int sbase = (o == 0) ? 0 : ((off <= 16) ? off : (24 + 8 * (o - 6)));
        const bool mine = (jq == (o & 3));
        #pragma unroll
        for (int r = 0; r < 4; ++r) {
            const int slot = sbase + rbase + r;
            const float4* gp = (const float4*)(sW2r + slot * W2PAD + j0);
            float4 g0 = gp[0], g1 = gp[1];
            float w = h[r][0] * g0.x + h[r][1] * g0.y + h[r][2] * g0.z + h[r][3] * g0.w
                    + h[r][4] * g1.x + h[r][5] * g1.y + h[r][6] * g1.z + h[r][7] * g1.w;
            w += __shfl_xor(w, 1, 64);    // combine jq bit 0 (DPP quad_perm)
            w += __shfl_xor(w, 2, 64);    // combine jq bit 1 (DPP quad_perm)
            if (mine)
                rws[(b * NROW + rbase + r) * WPAD + o] = w + sb2[slot];
        }
    }
    __syncthreads();

    // coalesced write-out: 128 rows x 12 floats = 384 float4
    {
        const float4* rv = (const float4*)rws;
        #pragma unroll 1
        for (int k = t; k < NROW * BATCH * 3; k += 128) {
            int row = k / 3, comp = k - row * 3;
            int bb = row >> 3, rr = row & 7;
            float4* dst = (float4*)(Wsp +
                ((size_t)(i * BATCH + bb) * NVEC + nbase + rr) * WPAD + comp * 4);
            *dst = rv[k];
        }
    }
}

// ---------------------------------------------------------------------------
// Kernel 2: FUSED 10-layer chain + final-projection partials.
// Block = (b, 4-dim chunk): V[1024][4] slice in LDS. 512 threads; thread n
// owns rows n AND n+512 in registers -> the offset-512 gather is a REGISTER
// read for both rows. Cross-wave reduction mapped so sred[w] (w=0..15)
// holds bitwise the same 16 partials as the 16-wave version.
// XCD-aware mapping: all 16 chunk-blocks of a b land on one XCD (L2 reuse
// of the per-layer 48 KB Wsp slab).
// grid (256), block 512.  [unchanged from round 5 — known-good]
// ---------------------------------------------------------------------------
__global__ __launch_bounds__(512) void k_chain(
    const float* __restrict__ data,   // [B][NVEC][NDIM]
    const float* __restrict__ Wsp,    // [NW][B][NVEC][WPAD]
    const float* __restrict__ Wf,     // [NVEC*NDIM][NCLS]
    float* __restrict__ part)         // [B][NCHUNK][NCLS]
{
    const int lin   = blockIdx.x;
    const int xcd   = lin & 7;
    const int slot  = lin >> 3;             // 0..31
    const int b     = (xcd << 1) | (slot >> 4);
    const int chunk = slot & 15;
    const int d0    = chunk * 4;
    const int n     = threadIdx.x;          // 0..511
    const int n2    = n + 512;

    __shared__ float4 bufA[NVEC];
    __shared__ float4 bufB[NVEC];

    float4 v0own = *(const float4*)(data + ((size_t)(b * NVEC) + n)  * NDIM + d0);
    float4 v1own = *(const float4*)(data + ((size_t)(b * NVEC) + n2) * NDIM + d0);
    bufA[n]  = v0own;
    bufA[n2] = v1own;

    // prefetch layer NW-1 weights for both rows
    const float* wbase = Wsp + (size_t)((NW - 1) * BATCH + b) * NVEC * WPAD;
    const float4* wp0 = (const float4*)(wbase + (size_t)n  * WPAD);
    const float4* wp1 = (const float4*)(wbase + (size_t)n2 * WPAD);
    float4 wa0 = wp0[0], wb0 = wp0[1], wc0 = wp0[2];
    float4 wa1 = wp1[0], wb1 = wp1[1], wc1 = wp1[2];
    __syncthreads();

    float4* cur = bufA;
    float4* nxt = bufB;

    for (int l = 0; l < NW; ++l) {
        float4 na0, nb0, nc0, na1, nb1, nc1;
        if (l < NW - 1) {   // prefetch next layer (in flight across barrier)
            const float* nbase_p = Wsp + (size_t)((NW - 2 - l) * BATCH + b) * NVEC * WPAD;
            const float4* q0 = (const float4*)(nbase_p + (size_t)n  * WPAD);
            const float4* q1 = (const float4*)(nbase_p + (size_t)n2 * WPAD);
            na0 = q0[0]; nb0 = q0[1]; nc0 = q0[2];
            na1 = q1[0]; nb1 = q1[1]; nc1 = q1[2];
        }
        const float wg0[12] = {wa0.x, wa0.y, wa0.z, wa0.w,
                               wb0.x, wb0.y, wb0.z, wb0.w,
                               wc0.x, wc0.y, wc0.z, wc0.w};
        const float wg1[12] = {wa1.x, wa1.y, wa1.z, wa1.w,
                               wb1.x, wb1.y, wb1.z, wb1.w,
                               wc1.x, wc1.y, wc1.z, wc1.w};
        // row n (diag + offsets; offset 512 comes from v1own register)
        float4 acc0;
        acc0.x = v0own.x + wg0[0] * v0own.x;
        acc0.y = v0own.y + wg0[0] * v0own.y;
        acc0.z = v0own.z + wg0[0] * v0own.z;
        acc0.w = v0own.w + wg0[0] * v0own.w;
        #pragma unroll
        for (int o = 1; o < NOFF; ++o) {
            int off = 1 << (o - 1);
            float4 vv = (off == 512) ? v1own : cur[(n + off) & (NVEC - 1)];
            acc0.x += wg0[o] * vv.x; acc0.y += wg0[o] * vv.y;
            acc0.z += wg0[o] * vv.z; acc0.w += wg0[o] * vv.w;
        }
        // row n+512 (offset 512 wraps to row n -> v0own register)
        float4 acc1;
        acc1.x = v1own.x + wg1[0] * v1own.x;
        acc1.y = v1own.y + wg1[0] * v1own.y;
        acc1.z = v1own.z + wg1[0] * v1own.z;
        acc1.w = v1own.w + wg1[0] * v1own.w;
        #pragma unroll
        for (int o = 1; o < NOFF; ++o) {
            int off = 1 << (o - 1);
            float4 vv = (off == 512) ? v0own : cur[(n2 + off) & (NVEC - 1)];
            acc1.x += wg1[o] * vv.x; acc1.y += wg1[o] * vv.y;
            acc1.z += wg1[o] * vv.z; acc1.w += wg1[o] * vv.w;
        }
        nxt[n]  = acc0;
        nxt[n2] = acc1;
        v0own = acc0;
        v1own = acc1;
        __syncthreads();
        float4* tmp = cur; cur = nxt; nxt = tmp;
        if (l < NW - 1) {
            wa0 = na0; wb0 = nb0; wc0 = nc0;
            wa1 = na1; wb1 = nb1; wc1 = nc1;
        }
    }

    // fused final projection partials for both rows — from registers
    float p0[NCLS], p1[NCLS];
    #pragma unroll
    for (int c = 0; c < NCLS; ++c) { p0[c] = 0.0f; p1[c] = 0.0f; }
    {
        float vs0[4] = {v0own.x, v0own.y, v0own.z, v0own.w};
        float vs1[4] = {v1own.x, v1own.y, v1own.z, v1own.w};
        const float4* wfv0 = (const float4*)(Wf + ((size_t)(n  * NDIM + d0)) * NCLS);
        const float4* wfv1 = (const float4*)(Wf + ((size_t)(n2 * NDIM + d0)) * NCLS);
        float wf0[40], wf1[40];
        #pragma unroll
        for (int k = 0; k < 10; ++k) {
            float4 u0 = wfv0[k], u1 = wfv1[k];
            wf0[k * 4 + 0] = u0.x; wf0[k * 4 + 1] = u0.y;
            wf0[k * 4 + 2] = u0.z; wf0[k * 4 + 3] = u0.w;
            wf1[k * 4 + 0] = u1.x; wf1[k * 4 + 1] = u1.y;
            wf1[k * 4 + 2] = u1.z; wf1[k * 4 + 3] = u1.w;
        }
        #pragma unroll
        for (int d = 0; d < 4; ++d)
            #pragma unroll
            for (int cls = 0; cls < NCLS; ++cls) {
                p0[cls] += vs0[d] * wf0[d * NCLS + cls];
                p1[cls] += vs1[d] * wf1[d * NCLS + cls];
            }
    }

    // reduce -> 10 values; wave wv emits partials of old waves wv and wv+8
    const int lane = n & 63, wv = n >> 6;   // 8 waves
    float* sred = (float*)nxt;              // dead buffer
    #pragma unroll
    for (int cls = 0; cls < NCLS; ++cls) {
        float v0 = p0[cls];
        float v1 = p1[cls];
        #pragma unroll
        for (int s = 32; s > 0; s >>= 1) {
            v0 += __shfl_down(v0, s, 64);
            v1 += __shfl_down(v1, s, 64);
        }
        if (lane == 0) {
            sred[wv * NCLS + cls]       = v0;
            sred[(wv + 8) * NCLS + cls] = v1;
        }
    }
    __syncthreads();
    if (n < NCLS) {
        float s = 0.0f;
        #pragma unroll
        for (int w = 0; w < 16; ++w) s += sred[w * NCLS + n];
        part[(size_t)(b * NCHUNK + chunk) * NCLS + n] = s;
    }
}

// ---------------------------------------------------------------------------
__global__ __launch_bounds__(256) void k_finish(
    const float* __restrict__ part, const float* __restrict__ bias,
    float* __restrict__ out)
{
    int t = threadIdx.x;
    if (t < BATCH * NCLS) {
        int b = t / NCLS, cls = t % NCLS;
        float s = bias[cls];
        #pragma unroll
        for (int ch = 0; ch < NCHUNK; ++ch)
            s += part[(size_t)(b * NCHUNK + ch) * NCLS + cls];
        out[t] = s;
    }
}

// ---------------------------------------------------------------------------
extern "C" void kernel_launch(void* const* d_in, const int* in_sizes, int n_in,
                              void* d_out, int out_size, void* d_ws, size_t ws_size,
                              hipStream_t stream) {
    const float* data = (const float*)d_in[0];
    const float* fW1  = (const float*)d_in[1];
    const float* fb1  = (const float*)d_in[2];
    const float* fW2  = (const float*)d_in[3];
    const float* fb2  = (const float*)d_in[4];
    const float* fWf  = (const float*)d_in[5];
    const float* fbf  = (const float*)d_in[6];
    float* out = (float*)d_out;

    float* ws   = (float*)d_ws;
    float* Wsp  = ws;                                         // NW*B*NVEC*WPAD = 1,966,080 f
    float* part = Wsp + (size_t)NW * BATCH * NVEC * WPAD;     // B*NCHUNK*NCLS = 2,560 f

    k_weights<<<dim3(NVEC / NROW, NW), 128, 0, stream>>>(
        data, fW1, fb1, fW2, fb2, Wsp);
    k_chain<<<dim3(NCHUNK * BATCH), 512, 0, stream>>>(data, Wsp, fWf, part);
    k_finish<<<dim3(1), 256, 0, stream>>>(part, fbf, out);
}